// Round 16
// baseline (84.760 us; speedup 1.0000x reference)
//
#include <hip/hip_runtime.h>
#include <math.h>

#define HEADS   4
#define DH      32
#define NB      4096      // tokens per batch (D*H*W)
#define BATCH   2
#define C_IN    128
#define QKV_COLS 384
#define TOTROWS 8192      // BATCH * NB
#define ATT_EPS 1e-12f
#define C1      14.42695040888963f   // SCALE * log2(e), prefolded into Q
#define QROWS   8         // rows per qkv block (grid 1024)
#define OROWS   8         // rows per outproj block (grid 1024)

typedef __attribute__((ext_vector_type(16))) float f32x16;
typedef _Float16 f16x8 __attribute__((ext_vector_type(8)));
typedef __fp16 fp16x2 __attribute__((ext_vector_type(2)));   // cvt_pkrtz return type
typedef unsigned short u16;

// fp16 RTN conversion (default float->_Float16 rounding)
__device__ __forceinline__ u16 f16b(float a) {
  union { _Float16 h; u16 u; } t; t.h = (_Float16)a; return t.u;
}
__device__ __forceinline__ unsigned pkf16rtn(float a, float b) {
  return (unsigned)f16b(a) | ((unsigned)f16b(b) << 16);
}
// pack 2 f32 -> 2 f16 (RTZ), single instruction (P values only)
union Uh2 { fp16x2 h; unsigned u; };
__device__ __forceinline__ unsigned pkf16(float a, float b) {
  Uh2 t; t.h = __builtin_amdgcn_cvt_pkrtz(a, b); return t.u;
}
union U8h { unsigned u[4]; f16x8 h8; };
__device__ __forceinline__ f16x8 mk8h(unsigned a, unsigned b, unsigned c, unsigned d) {
  U8h t; t.u[0] = a; t.u[1] = b; t.u[2] = c; t.u[3] = d; return t.h8;
}
// v_permlane32_swap_b32 a,b. SAFE ONLY when a and b hold distinct values
// (else regalloc may coalesce them into one register) — see R4 post-mortem.
__device__ __forceinline__ void pl32swap(unsigned& a, unsigned& b) {
  asm("v_permlane32_swap_b32 %0, %1" : "+v"(a), "+v"(b));
}
#define GL16(gp, lp)                                                        \
  __builtin_amdgcn_global_load_lds(                                         \
      (const __attribute__((address_space(1))) void*)(gp),                  \
      (__attribute__((address_space(3))) void*)(lp), 16, 0, 0)

// ---------------------------------------------------------------------------
// QKV GEMM (x @ w_qkv) + fused L2-normalize of q,k. NO LDS (R12: scalar x
// loads; LDS-broadcast version was LDS-pipe-bound). Unchanged from R12.
// ---------------------------------------------------------------------------
__global__ __launch_bounds__(384) void qkv_kernel(
    const float* __restrict__ x, const float* __restrict__ w,
    float* __restrict__ Qs, u16* __restrict__ K16, u16* __restrict__ VT16) {
  const int tid = threadIdx.x;
  const int r0  = blockIdx.x * QROWS;

  float4 a4[QROWS];
#pragma unroll
  for (int r = 0; r < QROWS; ++r) a4[r] = make_float4(0.f, 0.f, 0.f, 0.f);

  for (int c4 = 0; c4 < 32; ++c4) {
    const float wv0 = w[(c4 * 4 + 0) * QKV_COLS + tid];
    const float wv1 = w[(c4 * 4 + 1) * QKV_COLS + tid];
    const float wv2 = w[(c4 * 4 + 2) * QKV_COLS + tid];
    const float wv3 = w[(c4 * 4 + 3) * QKV_COLS + tid];
#pragma unroll
    for (int r = 0; r < QROWS; ++r) {
      const float* xr = x + (size_t)(r0 + r) * C_IN + c4 * 4;  // uniform -> s_load
      a4[r].x = fmaf(xr[0], wv0, a4[r].x);
      a4[r].y = fmaf(xr[1], wv1, a4[r].y);
      a4[r].z = fmaf(xr[2], wv2, a4[r].z);
      a4[r].w = fmaf(xr[3], wv3, a4[r].w);
    }
  }

  float acc[QROWS];
#pragma unroll
  for (int r = 0; r < QROWS; ++r)
    acc[r] = (a4[r].x + a4[r].y) + (a4[r].z + a4[r].w);

  const int part = tid >> 7;   // 0=q 1=k 2=v (wave-uniform)
  if (part < 2) {
#pragma unroll
    for (int r = 0; r < QROWS; ++r) {
      float s = acc[r] * acc[r];
      s += __shfl_xor(s, 1, 32);
      s += __shfl_xor(s, 2, 32);
      s += __shfl_xor(s, 4, 32);
      s += __shfl_xor(s, 8, 32);
      s += __shfl_xor(s, 16, 32);
      acc[r] *= 1.0f / fmaxf(sqrtf(s), ATT_EPS);
    }
  }

  const int h = (tid >> 5) & 3, d = tid & 31;
  const int b = r0 >> 12, n0 = r0 & (NB - 1);
  const int bh = b * HEADS + h;
  if (part == 0) {
    float* dst = Qs + ((size_t)bh * NB + n0) * DH + d;
#pragma unroll
    for (int r = 0; r < QROWS; ++r) dst[(size_t)r * DH] = acc[r] * C1;
  } else if (part == 1) {
    const size_t kb = ((size_t)bh * NB + n0) * DH + d;
#pragma unroll
    for (int r = 0; r < QROWS; ++r) K16[kb + (size_t)r * DH] = f16b(acc[r]);
  } else {
    const size_t vb = ((size_t)bh * DH + d) * NB + n0;
#pragma unroll
    for (int r = 0; r < QROWS; r += 4) {
      uint2 hv;
      hv.x = pkf16rtn(acc[r + 0], acc[r + 1]);
      hv.y = pkf16rtn(acc[r + 2], acc[r + 3]);
      *(uint2*)(VT16 + vb + r) = hv;
    }
  }
}

// ---------------------------------------------------------------------------
// MFMA flash attention, fixed softmax max (|q.k|<=1 after L2 norm => log2
// scores bounded by C1; 2^-C1 cancels in O/L). No max tracking, no rescale.
// R16: OCCUPANCY restructure. Block 512 = 8 waves = 8 KV-splits x 1 q-tile
// (32 q, 512 keys = 16 tiles each). Grid = 128 qp x 8 bh = 1024 blocks
// = 4 blocks/CU -> target 32 waves/CU (R13's grid-512 structure capped at
// 2 blocks/CU, occupancy 33%, lockstep stalls ~2/3 of wall; R14/R15 showed
// direct loads expose latency and prefetch can't be pinned at source level).
// K staged in LDS (dbuf, 32KB, swizzled); V loaded direct per-lane (R14-
// verified pattern — hides under QK+softmax with 8 waves/SIMD TLP).
// __launch_bounds__(512,8) forces VGPR<=64 for 8 waves/SIMD (R14 ran at 36).
// QK^T and PV: fp16 single-term (R12). XCD-pinned: bh = id&7.
// ---------------------------------------------------------------------------
__global__ __launch_bounds__(512, 8) void attn_kernel(
    const float* __restrict__ Qs, const u16* __restrict__ K16,
    const u16* __restrict__ VT16, float* __restrict__ AO) {
  // [buf][split][2048B] K planes only = 32 KB; merge overlays this after loop
  __shared__ __align__(16) char sbuf[2][8][2048];

  const int tid  = threadIdx.x;
  const int lane = tid & 63;
  const int su   = tid >> 6;        // KV split 0..7 (one wave each)
  const int q    = lane & 31;
  const int hi   = lane >> 5;
  const int bh   = blockIdx.x & 7;  // XCD-pinned panel
  const int qp   = blockIdx.x >> 3; // q-tile 0..127

  // ---- Q fragments (fp16 RTN); Q pre-scaled by C1 ----
  const int nrow = qp * 32 + q;
  const float* qrow = Qs + ((size_t)bh * NB + nrow) * DH;
  f16x8 fq16[2];
#pragma unroll
  for (int sl = 0; sl < 2; ++sl) {
    const int d0 = sl * 16 + hi * 8;
    const float4 a = *(const float4*)(qrow + d0);
    const float4 b = *(const float4*)(qrow + d0 + 4);
    fq16[sl] = mk8h(pkf16rtn(a.x, a.y), pkf16rtn(a.z, a.w),
                    pkf16rtn(b.x, b.y), pkf16rtn(b.z, b.w));
  }

  // ---- K staging map: flat idx = tid + it*512 over 8 planes x 2048B ----
  const u16* gp[2]; int ldso[2];
#pragma unroll
  for (int it = 0; it < 2; ++it) {
    const int idx  = tid + it * 512;    // 0..1023
    const int sp   = idx >> 7;          // split plane 0..7
    const int s    = idx & 127;
    const int rtt  = s >> 2;            // key row 0..31
    const int ps   = s & 3;             // physical 16B slot
    const int slot = ((ps ^ ((rtt >> 1) & 3)) << 3);   // pre-swz src, u16
    gp[it]  = K16 + (size_t)bh * NB * DH + (size_t)(sp * 512 + rtt) * DH + slot;
    ldso[it] = idx * 16;
  }
  char* const sb = (char*)sbuf;
  auto stage = [&](int buf) {
#pragma unroll
    for (int it = 0; it < 2; ++it) {
      GL16(gp[it], sb + buf * 16384 + ldso[it]);
      gp[it] += 32 * DH;
    }
  };

  // V direct per-lane pointer (advances 32 keys/tile)
  const u16* vp = VT16 + (size_t)bh * DH * NB + (size_t)q * NB + su * 512 + hi * 8;

  // swizzled K read offsets, constant per wave
  const int swq = (q >> 1) & 3;
  int koff[2];
#pragma unroll
  for (int i = 0; i < 2; ++i) koff[i] = q * 64 + (((i * 2 + hi) ^ swq) << 4);

  f32x16 oa, zz;
#pragma unroll
  for (int r = 0; r < 16; ++r) { oa[r] = 0.f; zz[r] = 0.f; }
  float lrun = 0.f;

  stage(0);
  __syncthreads();

  for (int t = 0; t < 16; ++t) {
    const int cur = t & 1;
    if (t < 15) stage(cur ^ 1);

    // V fragments for this tile (direct; consumed after QK+softmax)
    const f16x8 fv0 = *(const f16x8*)(vp);
    const f16x8 fv1 = *(const f16x8*)(vp + 16);
    vp += 32;

    const char* ck = sb + cur * 16384 + su * 2048;

    // ---- QK^T (single-term fp16), S^T[key][q]; C-in = const zero ----
    f32x16 sa;
    __builtin_amdgcn_s_setprio(1);
    {
      const f16x8 fk0 = *(const f16x8*)(ck + koff[0]);
      const f16x8 fk1 = *(const f16x8*)(ck + koff[1]);
      sa = __builtin_amdgcn_mfma_f32_32x32x16_f16(fk0, fq16[0], zz, 0, 0, 0);
      sa = __builtin_amdgcn_mfma_f32_32x32x16_f16(fk1, fq16[1], sa, 0, 0, 0);
    }
    __builtin_amdgcn_s_setprio(0);

    // ---- softmax, fixed max: raw v_exp_f32 (inputs bounded by ±~C1) ----
    float e[16], lsum = 0.f;
#pragma unroll
    for (int r = 0; r < 16; ++r) {
      e[r] = __builtin_amdgcn_exp2f(sa[r]);
      lsum += e[r];
    }
    lrun += lsum;

    // ---- P pack (fp16 RTZ) + permlane32_swap distribution, PV 1-term ----
    __builtin_amdgcn_s_setprio(1);
    {
      unsigned x0 = pkf16(e[0], e[1]), x1 = pkf16(e[2], e[3]);
      unsigned y0 = pkf16(e[4], e[5]), y1 = pkf16(e[6], e[7]);
      pl32swap(x0, y0);    // distinct values: safe
      pl32swap(x1, y1);
      oa = __builtin_amdgcn_mfma_f32_32x32x16_f16(fv0, mk8h(x0, x1, y0, y1),
                                                  oa, 0, 0, 0);
      unsigned z0 = pkf16(e[8], e[9]),   z1 = pkf16(e[10], e[11]);
      unsigned t0 = pkf16(e[12], e[13]), t1 = pkf16(e[14], e[15]);
      pl32swap(z0, t0);
      pl32swap(z1, t1);
      oa = __builtin_amdgcn_mfma_f32_32x32x16_f16(fv1, mk8h(z0, z1, t0, t1),
                                                  oa, 0, 0, 0);
    }
    __builtin_amdgcn_s_setprio(0);
    __syncthreads();   // drains gload_lds (implicit vmcnt(0)) + LDS reads
  }

  // ---- 8-way split merge via LDS (plain sums — common fixed max) ----
  // Overlays the (dead) K staging LDS: 7*32*33 + 7*32 floats = 29.8KB < 32KB.
  float* const mO = (float*)sbuf;             // [s(0..6)][q][33]
  float* const mL = mO + 7 * 32 * 33;         // [s][q]
  const float Lfull = lrun + __shfl_xor(lrun, 32);
  if (su != 0) {
    const int sidx = (su - 1) * 32 + q;
    if (hi == 0) mL[sidx] = Lfull;
#pragma unroll
    for (int r = 0; r < 16; ++r) {
      const int d = (r & 3) + 8 * (r >> 2) + 4 * hi;
      mO[sidx * 33 + d] = oa[r];
    }
  }
  __syncthreads();
  if (su == 0) {
    float Lt = Lfull;
#pragma unroll
    for (int s = 0; s < 7; ++s) Lt += mL[s * 32 + q];
    const float inv = 1.0f / Lt;
    const int b = bh >> 2, h = bh & 3;
    float* dst = AO + ((size_t)(b * NB + nrow)) * 128 + h * DH;
#pragma unroll
    for (int r = 0; r < 16; ++r) {
      const int d = (r & 3) + 8 * (r >> 2) + 4 * hi;
      float v = oa[r];
#pragma unroll
      for (int s = 0; s < 7; ++s) v += mO[(s * 32 + q) * 33 + d];
      dst[d] = v * inv;
    }
  }
}

// ---------------------------------------------------------------------------
// out-proj GEMM: AO[8192][128] @ w_out[128][128] + b_out. NO LDS (R12).
// In-place safe: all AO reads complete before the barrier; stores after.
// ---------------------------------------------------------------------------
__global__ __launch_bounds__(128) void outproj_kernel(
    const float* __restrict__ AO, const float* __restrict__ w,
    const float* __restrict__ bias, float* __restrict__ out) {
  const int tid = threadIdx.x;
  const int r0  = blockIdx.x * OROWS;

  float4 a4[OROWS];
#pragma unroll
  for (int r = 0; r < OROWS; ++r) a4[r] = make_float4(0.f, 0.f, 0.f, 0.f);

  for (int c4 = 0; c4 < 32; ++c4) {
    const float wv0 = w[(c4 * 4 + 0) * 128 + tid];
    const float wv1 = w[(c4 * 4 + 1) * 128 + tid];
    const float wv2 = w[(c4 * 4 + 2) * 128 + tid];
    const float wv3 = w[(c4 * 4 + 3) * 128 + tid];
#pragma unroll
    for (int r = 0; r < OROWS; ++r) {
      const float* xr = AO + (size_t)(r0 + r) * 128 + c4 * 4;  // uniform -> s_load
      a4[r].x = fmaf(xr[0], wv0, a4[r].x);
      a4[r].y = fmaf(xr[1], wv1, a4[r].y);
      a4[r].z = fmaf(xr[2], wv2, a4[r].z);
      a4[r].w = fmaf(xr[3], wv3, a4[r].w);
    }
  }

  __syncthreads();   // all AO reads of this block's rows complete before stores

  const float bv = bias[tid];
#pragma unroll
  for (int r = 0; r < OROWS; ++r) {
    const float acc = (a4[r].x + a4[r].y) + (a4[r].z + a4[r].w);
    out[(size_t)(r0 + r) * 128 + tid] = acc + bv;
  }
}

// ---------------------------------------------------------------------------
extern "C" void kernel_launch(void* const* d_in, const int* in_sizes, int n_in,
                              void* d_out, int out_size, void* d_ws, size_t ws_size,
                              hipStream_t stream) {
  (void)in_sizes; (void)n_in; (void)out_size; (void)ws_size;
  const float* x     = (const float*)d_in[0];
  const float* w_qkv = (const float*)d_in[1];
  const float* w_out = (const float*)d_in[2];
  const float* b_out = (const float*)d_in[3];
  float* out = (float*)d_out;

  float* ws = (float*)d_ws;
  float* Qs = ws;                               // 4 MB fp32 [bh][n][32]
  u16* K16  = (u16*)(ws + 1048576);             // 2 MB
  u16* VT16 = K16 + 1048576;                    // 2 MB
  float* AO = out;                              // in-place

  qkv_kernel<<<TOTROWS / QROWS, 384, 0, stream>>>(x, w_qkv, Qs, K16, VT16);
  attn_kernel<<<1024, 512, 0, stream>>>(Qs, K16, VT16, AO);
  outproj_kernel<<<TOTROWS / OROWS, 128, 0, stream>>>(AO, w_out, b_out, out);
}

// Round 18
// 73.622 us; speedup vs baseline: 1.1513x; 1.1513x over previous
//
#include <hip/hip_runtime.h>
#include <math.h>

#define HEADS   4
#define DH      32
#define NB      4096      // tokens per batch (D*H*W)
#define BATCH   2
#define C_IN    128
#define QKV_COLS 384
#define TOTROWS 8192      // BATCH * NB
#define ATT_EPS 1e-12f
#define C1      14.42695040888963f   // SCALE * log2(e), prefolded into Q
#define QROWS   8         // rows per qkv block (grid 1024)
#define OROWS   8         // rows per outproj block (grid 1024)

typedef __attribute__((ext_vector_type(16))) float f32x16;
typedef _Float16 f16x8 __attribute__((ext_vector_type(8)));
typedef __fp16 fp16x2 __attribute__((ext_vector_type(2)));   // cvt_pkrtz return type
typedef unsigned short u16;

// fp16 RTN conversion (default float->_Float16 rounding)
__device__ __forceinline__ u16 f16b(float a) {
  union { _Float16 h; u16 u; } t; t.h = (_Float16)a; return t.u;
}
__device__ __forceinline__ unsigned pkf16rtn(float a, float b) {
  return (unsigned)f16b(a) | ((unsigned)f16b(b) << 16);
}
// pack 2 f32 -> 2 f16 (RTZ), single instruction (P values only)
union Uh2 { fp16x2 h; unsigned u; };
__device__ __forceinline__ unsigned pkf16(float a, float b) {
  Uh2 t; t.h = __builtin_amdgcn_cvt_pkrtz(a, b); return t.u;
}
union U8h { unsigned u[4]; f16x8 h8; };
__device__ __forceinline__ f16x8 mk8h(unsigned a, unsigned b, unsigned c, unsigned d) {
  U8h t; t.u[0] = a; t.u[1] = b; t.u[2] = c; t.u[3] = d; return t.h8;
}
// v_permlane32_swap_b32 a,b. SAFE ONLY when a and b hold distinct values
// (else regalloc may coalesce them into one register) — see R4 post-mortem.
__device__ __forceinline__ void pl32swap(unsigned& a, unsigned& b) {
  asm("v_permlane32_swap_b32 %0, %1" : "+v"(a), "+v"(b));
}
#define GL16(gp, lp)                                                        \
  __builtin_amdgcn_global_load_lds(                                         \
      (const __attribute__((address_space(1))) void*)(gp),                  \
      (__attribute__((address_space(3))) void*)(lp), 16, 0, 0)

// ---------------------------------------------------------------------------
// QKV GEMM (x @ w_qkv) + fused L2-normalize of q,k. NO LDS (R12: scalar x
// loads; LDS-broadcast version was LDS-pipe-bound). Unchanged from R12.
// ---------------------------------------------------------------------------
__global__ __launch_bounds__(384) void qkv_kernel(
    const float* __restrict__ x, const float* __restrict__ w,
    float* __restrict__ Qs, u16* __restrict__ K16, u16* __restrict__ VT16) {
  const int tid = threadIdx.x;
  const int r0  = blockIdx.x * QROWS;

  float4 a4[QROWS];
#pragma unroll
  for (int r = 0; r < QROWS; ++r) a4[r] = make_float4(0.f, 0.f, 0.f, 0.f);

  for (int c4 = 0; c4 < 32; ++c4) {
    const float wv0 = w[(c4 * 4 + 0) * QKV_COLS + tid];
    const float wv1 = w[(c4 * 4 + 1) * QKV_COLS + tid];
    const float wv2 = w[(c4 * 4 + 2) * QKV_COLS + tid];
    const float wv3 = w[(c4 * 4 + 3) * QKV_COLS + tid];
#pragma unroll
    for (int r = 0; r < QROWS; ++r) {
      const float* xr = x + (size_t)(r0 + r) * C_IN + c4 * 4;  // uniform -> s_load
      a4[r].x = fmaf(xr[0], wv0, a4[r].x);
      a4[r].y = fmaf(xr[1], wv1, a4[r].y);
      a4[r].z = fmaf(xr[2], wv2, a4[r].z);
      a4[r].w = fmaf(xr[3], wv3, a4[r].w);
    }
  }

  float acc[QROWS];
#pragma unroll
  for (int r = 0; r < QROWS; ++r)
    acc[r] = (a4[r].x + a4[r].y) + (a4[r].z + a4[r].w);

  const int part = tid >> 7;   // 0=q 1=k 2=v (wave-uniform)
  if (part < 2) {
#pragma unroll
    for (int r = 0; r < QROWS; ++r) {
      float s = acc[r] * acc[r];
      s += __shfl_xor(s, 1, 32);
      s += __shfl_xor(s, 2, 32);
      s += __shfl_xor(s, 4, 32);
      s += __shfl_xor(s, 8, 32);
      s += __shfl_xor(s, 16, 32);
      acc[r] *= 1.0f / fmaxf(sqrtf(s), ATT_EPS);
    }
  }

  const int h = (tid >> 5) & 3, d = tid & 31;
  const int b = r0 >> 12, n0 = r0 & (NB - 1);
  const int bh = b * HEADS + h;
  if (part == 0) {
    float* dst = Qs + ((size_t)bh * NB + n0) * DH + d;
#pragma unroll
    for (int r = 0; r < QROWS; ++r) dst[(size_t)r * DH] = acc[r] * C1;
  } else if (part == 1) {
    const size_t kb = ((size_t)bh * NB + n0) * DH + d;
#pragma unroll
    for (int r = 0; r < QROWS; ++r) K16[kb + (size_t)r * DH] = f16b(acc[r]);
  } else {
    const size_t vb = ((size_t)bh * DH + d) * NB + n0;
#pragma unroll
    for (int r = 0; r < QROWS; r += 4) {
      uint2 hv;
      hv.x = pkf16rtn(acc[r + 0], acc[r + 1]);
      hv.y = pkf16rtn(acc[r + 2], acc[r + 3]);
      *(uint2*)(VT16 + vb + r) = hv;
    }
  }
}

// ---------------------------------------------------------------------------
// MFMA flash attention, fixed softmax max (|q.k|<=1 after L2 norm => log2
// scores bounded by C1; 2^-C1 cancels in O/L). No max tracking, no rescale.
// R18 = R17 + the missing pre-publish __syncthreads (R17's NaN was the merge
// overlay clobbering other waves' LIVE staging slices — without main-loop
// barriers, nothing aligned the waves before the overlay. The barrier-free
// pipeline itself audits clean.)
// Block 512 = 8 waves = 8 KV-splits x one 32-q tile; grid = 128 qp x 8 bh
// (XCD-pinned bh = id&7). Each wave owns a PRIVATE 8KB LDS slice (2 bufs x
// (K 2KB + V 2KB)) staged via global_load_lds — single-wave ownership means
// NO __syncthreads in the main loop; ordering is counted s_waitcnt vmcnt(4)
// (next tile's 4 loads stay in flight while current computes).
// QK^T and PV: fp16 single-term (R12).
// ---------------------------------------------------------------------------
__global__ __launch_bounds__(512, 4) void attn_kernel(
    const float* __restrict__ Qs, const u16* __restrict__ K16,
    const u16* __restrict__ VT16, float* __restrict__ AO) {
  // [wave][buf][plane: 0=K 1=V][2048B] = 64 KB; merge overlays after loop
  __shared__ __align__(16) char sbuf[8][2][2][2048];

  const int tid  = threadIdx.x;
  const int lane = tid & 63;
  const int su   = tid >> 6;        // KV split 0..7 (one wave each)
  const int q    = lane & 31;
  const int hi   = lane >> 5;
  const int bh   = blockIdx.x & 7;  // XCD-pinned panel
  const int qp   = blockIdx.x >> 3; // q-tile 0..127

  // ---- Q fragments (fp16 RTN); Q pre-scaled by C1 ----
  const int nrow = qp * 32 + q;
  const float* qrow = Qs + ((size_t)bh * NB + nrow) * DH;
  f16x8 fq16[2];
#pragma unroll
  for (int sl = 0; sl < 2; ++sl) {
    const int d0 = sl * 16 + hi * 8;
    const float4 a = *(const float4*)(qrow + d0);
    const float4 b = *(const float4*)(qrow + d0 + 4);
    fq16[sl] = mk8h(pkf16rtn(a.x, a.y), pkf16rtn(a.z, a.w),
                    pkf16rtn(b.x, b.y), pkf16rtn(b.z, b.w));
  }

  // ---- per-wave staging map: 4 GL16/tile (K: it 0-1, V: it 2-3) ----
  const u16* gp[4]; int ldso[4];
#pragma unroll
  for (int it = 0; it < 4; ++it) {
    const int idx  = (it & 1) * 64 + lane;   // 0..127 within the plane
    const int rtt  = idx >> 2;               // key row (K) / d row (V)
    const int ps   = idx & 3;                // physical 16B slot
    const int slot = ((ps ^ ((rtt >> 1) & 3)) << 3);   // pre-swz src, u16
    if (it < 2) {
      gp[it] = K16 + (size_t)bh * NB * DH + (size_t)(su * 512 + rtt) * DH + slot;
    } else {
      gp[it] = VT16 + (size_t)bh * DH * NB + (size_t)rtt * NB + su * 512 + slot;
    }
    ldso[it] = su * 8192 + (it >> 1) * 2048 + (it & 1) * 1024 + lane * 16;
  }
  char* const sb = (char*)sbuf;
  auto stage = [&](int buf) {
#pragma unroll
    for (int it = 0; it < 4; ++it) {
      GL16(gp[it], sb + ldso[it] + buf * 4096);
      gp[it] += (it < 2) ? 32 * DH : 32;
    }
  };

  // swizzled read offsets (within a 2048B plane), constant per wave
  const int swq = (q >> 1) & 3;
  int koff[2];
#pragma unroll
  for (int i = 0; i < 2; ++i) koff[i] = q * 64 + (((i * 2 + hi) ^ swq) << 4);

  f32x16 oa, zz;
#pragma unroll
  for (int r = 0; r < 16; ++r) { oa[r] = 0.f; zz[r] = 0.f; }
  float lrun = 0.f;

  stage(0);

  for (int t = 0; t < 16; ++t) {
    const int cur = t & 1;
    if (t < 15) {
      stage(cur ^ 1);                               // 4 loads in flight
      asm volatile("s_waitcnt vmcnt(4)" ::: "memory");   // tile t landed
    } else {
      asm volatile("s_waitcnt vmcnt(0)" ::: "memory");
    }
    __builtin_amdgcn_sched_barrier(0);   // rule #18: pin reads after waitcnt

    const char* ck = sb + su * 8192 + cur * 4096;
    const char* cv = ck + 2048;

    // ---- QK^T (single-term fp16), S^T[key][q]; C-in = const zero ----
    f32x16 sa;
    __builtin_amdgcn_s_setprio(1);
    {
      const f16x8 fk0 = *(const f16x8*)(ck + koff[0]);
      const f16x8 fk1 = *(const f16x8*)(ck + koff[1]);
      sa = __builtin_amdgcn_mfma_f32_32x32x16_f16(fk0, fq16[0], zz, 0, 0, 0);
      sa = __builtin_amdgcn_mfma_f32_32x32x16_f16(fk1, fq16[1], sa, 0, 0, 0);
    }
    __builtin_amdgcn_s_setprio(0);

    // ---- softmax, fixed max: raw v_exp_f32 (inputs bounded by ±~C1) ----
    float e[16], lsum = 0.f;
#pragma unroll
    for (int r = 0; r < 16; ++r) {
      e[r] = __builtin_amdgcn_exp2f(sa[r]);
      lsum += e[r];
    }
    lrun += lsum;

    // ---- P pack (fp16 RTZ) + permlane32_swap distribution, PV 1-term ----
    __builtin_amdgcn_s_setprio(1);
    {
      unsigned x0 = pkf16(e[0], e[1]), x1 = pkf16(e[2], e[3]);
      unsigned y0 = pkf16(e[4], e[5]), y1 = pkf16(e[6], e[7]);
      pl32swap(x0, y0);    // distinct values: safe
      pl32swap(x1, y1);
      const f16x8 fv0 = *(const f16x8*)(cv + koff[0]);
      oa = __builtin_amdgcn_mfma_f32_32x32x16_f16(fv0, mk8h(x0, x1, y0, y1),
                                                  oa, 0, 0, 0);
      unsigned z0 = pkf16(e[8], e[9]),   z1 = pkf16(e[10], e[11]);
      unsigned t0 = pkf16(e[12], e[13]), t1 = pkf16(e[14], e[15]);
      pl32swap(z0, t0);
      pl32swap(z1, t1);
      const f16x8 fv1 = *(const f16x8*)(cv + koff[1]);
      oa = __builtin_amdgcn_mfma_f32_32x32x16_f16(fv1, mk8h(z0, z1, t0, t1),
                                                  oa, 0, 0, 0);
    }
    __builtin_amdgcn_s_setprio(0);
    __builtin_amdgcn_sched_barrier(0);   // keep next stage() after reads
  }

  // ---- 8-way split merge via LDS (plain sums — common fixed max) ----
  // Overlays the (dead) staging LDS: 7*32*33 + 7*32 floats = 30.5KB < 64KB.
  // R18 FIX: barrier BEFORE publish — all waves must finish reading their
  // staging slices before anyone overwrites them (R17's NaN race).
  __syncthreads();
  float* const mO = (float*)sbuf;             // [s(0..6)][q][33]
  float* const mL = mO + 7 * 32 * 33;         // [s][q]
  const float Lfull = lrun + __shfl_xor(lrun, 32);
  if (su != 0) {
    const int sidx = (su - 1) * 32 + q;
    if (hi == 0) mL[sidx] = Lfull;
#pragma unroll
    for (int r = 0; r < 16; ++r) {
      const int d = (r & 3) + 8 * (r >> 2) + 4 * hi;
      mO[sidx * 33 + d] = oa[r];
    }
  }
  __syncthreads();
  if (su == 0) {
    float Lt = Lfull;
#pragma unroll
    for (int s = 0; s < 7; ++s) Lt += mL[s * 32 + q];
    const float inv = 1.0f / Lt;
    const int b = bh >> 2, h = bh & 3;
    float* dst = AO + ((size_t)(b * NB + nrow)) * 128 + h * DH;
#pragma unroll
    for (int r = 0; r < 16; ++r) {
      const int d = (r & 3) + 8 * (r >> 2) + 4 * hi;
      float v = oa[r];
#pragma unroll
      for (int s = 0; s < 7; ++s) v += mO[(s * 32 + q) * 33 + d];
      dst[d] = v * inv;
    }
  }
}

// ---------------------------------------------------------------------------
// out-proj GEMM: AO[8192][128] @ w_out[128][128] + b_out. NO LDS (R12).
// In-place safe: all AO reads complete before the barrier; stores after.
// ---------------------------------------------------------------------------
__global__ __launch_bounds__(128) void outproj_kernel(
    const float* __restrict__ AO, const float* __restrict__ w,
    const float* __restrict__ bias, float* __restrict__ out) {
  const int tid = threadIdx.x;
  const int r0  = blockIdx.x * OROWS;

  float4 a4[OROWS];
#pragma unroll
  for (int r = 0; r < OROWS; ++r) a4[r] = make_float4(0.f, 0.f, 0.f, 0.f);

  for (int c4 = 0; c4 < 32; ++c4) {
    const float wv0 = w[(c4 * 4 + 0) * 128 + tid];
    const float wv1 = w[(c4 * 4 + 1) * 128 + tid];
    const float wv2 = w[(c4 * 4 + 2) * 128 + tid];
    const float wv3 = w[(c4 * 4 + 3) * 128 + tid];
#pragma unroll
    for (int r = 0; r < OROWS; ++r) {
      const float* xr = AO + (size_t)(r0 + r) * 128 + c4 * 4;  // uniform -> s_load
      a4[r].x = fmaf(xr[0], wv0, a4[r].x);
      a4[r].y = fmaf(xr[1], wv1, a4[r].y);
      a4[r].z = fmaf(xr[2], wv2, a4[r].z);
      a4[r].w = fmaf(xr[3], wv3, a4[r].w);
    }
  }

  __syncthreads();   // all AO reads of this block's rows complete before stores

  const float bv = bias[tid];
#pragma unroll
  for (int r = 0; r < OROWS; ++r) {
    const float acc = (a4[r].x + a4[r].y) + (a4[r].z + a4[r].w);
    out[(size_t)(r0 + r) * 128 + tid] = acc + bv;
  }
}

// ---------------------------------------------------------------------------
extern "C" void kernel_launch(void* const* d_in, const int* in_sizes, int n_in,
                              void* d_out, int out_size, void* d_ws, size_t ws_size,
                              hipStream_t stream) {
  (void)in_sizes; (void)n_in; (void)out_size; (void)ws_size;
  const float* x     = (const float*)d_in[0];
  const float* w_qkv = (const float*)d_in[1];
  const float* w_out = (const float*)d_in[2];
  const float* b_out = (const float*)d_in[3];
  float* out = (float*)d_out;

  float* ws = (float*)d_ws;
  float* Qs = ws;                               // 4 MB fp32 [bh][n][32]
  u16* K16  = (u16*)(ws + 1048576);             // 2 MB
  u16* VT16 = K16 + 1048576;                    // 2 MB
  float* AO = out;                              // in-place

  qkv_kernel<<<TOTROWS / QROWS, 384, 0, stream>>>(x, w_qkv, Qs, K16, VT16);
  attn_kernel<<<1024, 512, 0, stream>>>(Qs, K16, VT16, AO);
  outproj_kernel<<<TOTROWS / OROWS, 128, 0, stream>>>(AO, w_out, b_out, out);
}

// Round 19
// 72.747 us; speedup vs baseline: 1.1651x; 1.0120x over previous
//
#include <hip/hip_runtime.h>
#include <math.h>

#define HEADS   4
#define DH      32
#define NB      4096      // tokens per batch (D*H*W)
#define BATCH   2
#define C_IN    128
#define QKV_COLS 384
#define TOTROWS 8192      // BATCH * NB
#define ATT_EPS 1e-12f
#define C1      14.42695040888963f   // SCALE * log2(e), prefolded into Q
#define QROWS   8         // rows per qkv block (grid 1024)
#define OROWS   8         // rows per outproj block (grid 1024)

typedef __attribute__((ext_vector_type(16))) float f32x16;
typedef _Float16 f16x8 __attribute__((ext_vector_type(8)));
typedef __fp16 fp16x2 __attribute__((ext_vector_type(2)));   // cvt_pkrtz return type
typedef unsigned short u16;

// fp16 RTN conversion (default float->_Float16 rounding)
__device__ __forceinline__ u16 f16b(float a) {
  union { _Float16 h; u16 u; } t; t.h = (_Float16)a; return t.u;
}
__device__ __forceinline__ unsigned pkf16rtn(float a, float b) {
  return (unsigned)f16b(a) | ((unsigned)f16b(b) << 16);
}
// pack 2 f32 -> 2 f16 (RTZ), single instruction (P values only)
union Uh2 { fp16x2 h; unsigned u; };
__device__ __forceinline__ unsigned pkf16(float a, float b) {
  Uh2 t; t.h = __builtin_amdgcn_cvt_pkrtz(a, b); return t.u;
}
union U8h { unsigned u[4]; f16x8 h8; };
__device__ __forceinline__ f16x8 mk8h(unsigned a, unsigned b, unsigned c, unsigned d) {
  U8h t; t.u[0] = a; t.u[1] = b; t.u[2] = c; t.u[3] = d; return t.h8;
}
// v_permlane32_swap_b32 a,b. SAFE ONLY when a and b hold distinct values
// (else regalloc may coalesce them into one register) — see R4 post-mortem.
__device__ __forceinline__ void pl32swap(unsigned& a, unsigned& b) {
  asm("v_permlane32_swap_b32 %0, %1" : "+v"(a), "+v"(b));
}
#define GL16(gp, lp)                                                        \
  __builtin_amdgcn_global_load_lds(                                         \
      (const __attribute__((address_space(1))) void*)(gp),                  \
      (__attribute__((address_space(3))) void*)(lp), 16, 0, 0)

// ---------------------------------------------------------------------------
// QKV GEMM (x @ w_qkv) + fused L2-normalize of q,k. NO LDS (R12: scalar x
// loads; LDS-broadcast version was LDS-pipe-bound). Unchanged from R12.
// ---------------------------------------------------------------------------
__global__ __launch_bounds__(384) void qkv_kernel(
    const float* __restrict__ x, const float* __restrict__ w,
    float* __restrict__ Qs, u16* __restrict__ K16, u16* __restrict__ VT16) {
  const int tid = threadIdx.x;
  const int r0  = blockIdx.x * QROWS;

  float4 a4[QROWS];
#pragma unroll
  for (int r = 0; r < QROWS; ++r) a4[r] = make_float4(0.f, 0.f, 0.f, 0.f);

  for (int c4 = 0; c4 < 32; ++c4) {
    const float wv0 = w[(c4 * 4 + 0) * QKV_COLS + tid];
    const float wv1 = w[(c4 * 4 + 1) * QKV_COLS + tid];
    const float wv2 = w[(c4 * 4 + 2) * QKV_COLS + tid];
    const float wv3 = w[(c4 * 4 + 3) * QKV_COLS + tid];
#pragma unroll
    for (int r = 0; r < QROWS; ++r) {
      const float* xr = x + (size_t)(r0 + r) * C_IN + c4 * 4;  // uniform -> s_load
      a4[r].x = fmaf(xr[0], wv0, a4[r].x);
      a4[r].y = fmaf(xr[1], wv1, a4[r].y);
      a4[r].z = fmaf(xr[2], wv2, a4[r].z);
      a4[r].w = fmaf(xr[3], wv3, a4[r].w);
    }
  }

  float acc[QROWS];
#pragma unroll
  for (int r = 0; r < QROWS; ++r)
    acc[r] = (a4[r].x + a4[r].y) + (a4[r].z + a4[r].w);

  const int part = tid >> 7;   // 0=q 1=k 2=v (wave-uniform)
  if (part < 2) {
#pragma unroll
    for (int r = 0; r < QROWS; ++r) {
      float s = acc[r] * acc[r];
      s += __shfl_xor(s, 1, 32);
      s += __shfl_xor(s, 2, 32);
      s += __shfl_xor(s, 4, 32);
      s += __shfl_xor(s, 8, 32);
      s += __shfl_xor(s, 16, 32);
      acc[r] *= 1.0f / fmaxf(sqrtf(s), ATT_EPS);
    }
  }

  const int h = (tid >> 5) & 3, d = tid & 31;
  const int b = r0 >> 12, n0 = r0 & (NB - 1);
  const int bh = b * HEADS + h;
  if (part == 0) {
    float* dst = Qs + ((size_t)bh * NB + n0) * DH + d;
#pragma unroll
    for (int r = 0; r < QROWS; ++r) dst[(size_t)r * DH] = acc[r] * C1;
  } else if (part == 1) {
    const size_t kb = ((size_t)bh * NB + n0) * DH + d;
#pragma unroll
    for (int r = 0; r < QROWS; ++r) K16[kb + (size_t)r * DH] = f16b(acc[r]);
  } else {
    const size_t vb = ((size_t)bh * DH + d) * NB + n0;
#pragma unroll
    for (int r = 0; r < QROWS; r += 4) {
      uint2 hv;
      hv.x = pkf16rtn(acc[r + 0], acc[r + 1]);
      hv.y = pkf16rtn(acc[r + 2], acc[r + 3]);
      *(uint2*)(VT16 + vb + r) = hv;
    }
  }
}

// ---------------------------------------------------------------------------
// MFMA flash attention, fixed softmax max (|q.k|<=1 after L2 norm => log2
// scores bounded by C1; 2^-C1 cancels in O/L). No max tracking, no rescale.
// R19: OCCUPANCY via single-buffer. R18 measured occupancy 32% (64KB LDS ->
// 2 blocks/CU) with VALUBusy 48% — VALU-issue-bound with idle slots. Here
// each wave has ONE 4KB slice (block 32KB): per tile, vmcnt(0) -> ds_read
// the 4 fragments into REGISTERS -> lgkmcnt(0) -> restage the same slice
// for t+1 (T14 split: values safe in regs) -> compute while loads fly.
// zz dropped (16 VGPRs), launch_bounds(512,7) -> target 3 blocks = 24
// waves/CU. Barrier-free main loop (wave-private slices, counted waits).
// Block 512 = 8 waves = 8 KV-splits x one 32-q tile; grid = 128 qp x 8 bh
// (XCD-pinned bh = id&7). QK^T and PV: fp16 single-term (R12).
// ---------------------------------------------------------------------------
__global__ __launch_bounds__(512, 7) void attn_kernel(
    const float* __restrict__ Qs, const u16* __restrict__ K16,
    const u16* __restrict__ VT16, float* __restrict__ AO) {
  // [wave][plane: 0=K 1=V][2048B] = 32 KB; merge overlays after loop
  __shared__ __align__(16) char sbuf[8][2][2048];

  const int tid  = threadIdx.x;
  const int lane = tid & 63;
  const int su   = tid >> 6;        // KV split 0..7 (one wave each)
  const int q    = lane & 31;
  const int hi   = lane >> 5;
  const int bh   = blockIdx.x & 7;  // XCD-pinned panel
  const int qp   = blockIdx.x >> 3; // q-tile 0..127

  // ---- Q fragments (fp16 RTN); Q pre-scaled by C1 ----
  const int nrow = qp * 32 + q;
  const float* qrow = Qs + ((size_t)bh * NB + nrow) * DH;
  f16x8 fq16[2];
#pragma unroll
  for (int sl = 0; sl < 2; ++sl) {
    const int d0 = sl * 16 + hi * 8;
    const float4 a = *(const float4*)(qrow + d0);
    const float4 b = *(const float4*)(qrow + d0 + 4);
    fq16[sl] = mk8h(pkf16rtn(a.x, a.y), pkf16rtn(a.z, a.w),
                    pkf16rtn(b.x, b.y), pkf16rtn(b.z, b.w));
  }

  // ---- per-wave staging map: 4 GL16/tile (K: it 0-1, V: it 2-3) ----
  const u16* gp[4]; int ldso[4];
#pragma unroll
  for (int it = 0; it < 4; ++it) {
    const int idx  = (it & 1) * 64 + lane;   // 0..127 within the plane
    const int rtt  = idx >> 2;               // key row (K) / d row (V)
    const int ps   = idx & 3;                // physical 16B slot
    const int slot = ((ps ^ ((rtt >> 1) & 3)) << 3);   // pre-swz src, u16
    if (it < 2) {
      gp[it] = K16 + (size_t)bh * NB * DH + (size_t)(su * 512 + rtt) * DH + slot;
    } else {
      gp[it] = VT16 + (size_t)bh * DH * NB + (size_t)rtt * NB + su * 512 + slot;
    }
    ldso[it] = su * 4096 + (it >> 1) * 2048 + (it & 1) * 1024 + lane * 16;
  }
  char* const sb = (char*)sbuf;
  auto stage = [&]() {
#pragma unroll
    for (int it = 0; it < 4; ++it) {
      GL16(gp[it], sb + ldso[it]);
      gp[it] += (it < 2) ? 32 * DH : 32;
    }
  };

  // swizzled read offsets (within a 2048B plane), constant per wave
  const int swq = (q >> 1) & 3;
  int koff[2];
#pragma unroll
  for (int i = 0; i < 2; ++i) koff[i] = q * 64 + (((i * 2 + hi) ^ swq) << 4);

  const char* ck = sb + su * 4096;
  const char* cv = ck + 2048;

  f32x16 oa;
#pragma unroll
  for (int r = 0; r < 16; ++r) oa[r] = 0.f;
  float lrun = 0.f;

  stage();   // tile 0 in flight

  for (int t = 0; t < 16; ++t) {
    // tile t's 4 loads have landed
    asm volatile("s_waitcnt vmcnt(0)" ::: "memory");
    __builtin_amdgcn_sched_barrier(0);

    // ---- LDS -> registers (frees the slice for restaging) ----
    const f16x8 fk0 = *(const f16x8*)(ck + koff[0]);
    const f16x8 fk1 = *(const f16x8*)(ck + koff[1]);
    const f16x8 fv0 = *(const f16x8*)(cv + koff[0]);
    const f16x8 fv1 = *(const f16x8*)(cv + koff[1]);
    asm volatile("s_waitcnt lgkmcnt(0)" ::: "memory");   // reads complete
    __builtin_amdgcn_sched_barrier(0);

    if (t < 15) stage();   // restage same slice for t+1; flies under compute

    // ---- QK^T (single-term fp16), S^T[key][q] ----
    f32x16 sa;
#pragma unroll
    for (int r = 0; r < 16; ++r) sa[r] = 0.f;
    __builtin_amdgcn_s_setprio(1);
    sa = __builtin_amdgcn_mfma_f32_32x32x16_f16(fk0, fq16[0], sa, 0, 0, 0);
    sa = __builtin_amdgcn_mfma_f32_32x32x16_f16(fk1, fq16[1], sa, 0, 0, 0);
    __builtin_amdgcn_s_setprio(0);

    // ---- softmax, fixed max: raw v_exp_f32 (inputs bounded by ±~C1) ----
    float e[16], lsum = 0.f;
#pragma unroll
    for (int r = 0; r < 16; ++r) {
      e[r] = __builtin_amdgcn_exp2f(sa[r]);
      lsum += e[r];
    }
    lrun += lsum;

    // ---- P pack (fp16 RTZ) + permlane32_swap distribution, PV 1-term ----
    __builtin_amdgcn_s_setprio(1);
    {
      unsigned x0 = pkf16(e[0], e[1]), x1 = pkf16(e[2], e[3]);
      unsigned y0 = pkf16(e[4], e[5]), y1 = pkf16(e[6], e[7]);
      pl32swap(x0, y0);    // distinct values: safe
      pl32swap(x1, y1);
      oa = __builtin_amdgcn_mfma_f32_32x32x16_f16(fv0, mk8h(x0, x1, y0, y1),
                                                  oa, 0, 0, 0);
      unsigned z0 = pkf16(e[8], e[9]),   z1 = pkf16(e[10], e[11]);
      unsigned t0 = pkf16(e[12], e[13]), t1 = pkf16(e[14], e[15]);
      pl32swap(z0, t0);
      pl32swap(z1, t1);
      oa = __builtin_amdgcn_mfma_f32_32x32x16_f16(fv1, mk8h(z0, z1, t0, t1),
                                                  oa, 0, 0, 0);
    }
    __builtin_amdgcn_s_setprio(0);
  }

  // ---- 8-way split merge via LDS (plain sums — common fixed max) ----
  // Overlays the (dead) staging LDS: 7*32*33 + 7*32 floats = 30.5KB < 32KB.
  // Pre-publish barrier: all waves done reading their slices (R17 lesson).
  __syncthreads();
  float* const mO = (float*)sbuf;             // [s(0..6)][q][33]
  float* const mL = mO + 7 * 32 * 33;         // [s][q]
  const float Lfull = lrun + __shfl_xor(lrun, 32);
  if (su != 0) {
    const int sidx = (su - 1) * 32 + q;
    if (hi == 0) mL[sidx] = Lfull;
#pragma unroll
    for (int r = 0; r < 16; ++r) {
      const int d = (r & 3) + 8 * (r >> 2) + 4 * hi;
      mO[sidx * 33 + d] = oa[r];
    }
  }
  __syncthreads();
  if (su == 0) {
    float Lt = Lfull;
#pragma unroll
    for (int s = 0; s < 7; ++s) Lt += mL[s * 32 + q];
    const float inv = 1.0f / Lt;
    const int b = bh >> 2, h = bh & 3;
    float* dst = AO + ((size_t)(b * NB + nrow)) * 128 + h * DH;
#pragma unroll
    for (int r = 0; r < 16; ++r) {
      const int d = (r & 3) + 8 * (r >> 2) + 4 * hi;
      float v = oa[r];
#pragma unroll
      for (int s = 0; s < 7; ++s) v += mO[(s * 32 + q) * 33 + d];
      dst[d] = v * inv;
    }
  }
}

// ---------------------------------------------------------------------------
// out-proj GEMM: AO[8192][128] @ w_out[128][128] + b_out. NO LDS (R12).
// In-place safe: all AO reads complete before the barrier; stores after.
// ---------------------------------------------------------------------------
__global__ __launch_bounds__(128) void outproj_kernel(
    const float* __restrict__ AO, const float* __restrict__ w,
    const float* __restrict__ bias, float* __restrict__ out) {
  const int tid = threadIdx.x;
  const int r0  = blockIdx.x * OROWS;

  float4 a4[OROWS];
#pragma unroll
  for (int r = 0; r < OROWS; ++r) a4[r] = make_float4(0.f, 0.f, 0.f, 0.f);

  for (int c4 = 0; c4 < 32; ++c4) {
    const float wv0 = w[(c4 * 4 + 0) * 128 + tid];
    const float wv1 = w[(c4 * 4 + 1) * 128 + tid];
    const float wv2 = w[(c4 * 4 + 2) * 128 + tid];
    const float wv3 = w[(c4 * 4 + 3) * 128 + tid];
#pragma unroll
    for (int r = 0; r < OROWS; ++r) {
      const float* xr = AO + (size_t)(r0 + r) * 128 + c4 * 4;  // uniform -> s_load
      a4[r].x = fmaf(xr[0], wv0, a4[r].x);
      a4[r].y = fmaf(xr[1], wv1, a4[r].y);
      a4[r].z = fmaf(xr[2], wv2, a4[r].z);
      a4[r].w = fmaf(xr[3], wv3, a4[r].w);
    }
  }

  __syncthreads();   // all AO reads of this block's rows complete before stores

  const float bv = bias[tid];
#pragma unroll
  for (int r = 0; r < OROWS; ++r) {
    const float acc = (a4[r].x + a4[r].y) + (a4[r].z + a4[r].w);
    out[(size_t)(r0 + r) * 128 + tid] = acc + bv;
  }
}

// ---------------------------------------------------------------------------
extern "C" void kernel_launch(void* const* d_in, const int* in_sizes, int n_in,
                              void* d_out, int out_size, void* d_ws, size_t ws_size,
                              hipStream_t stream) {
  (void)in_sizes; (void)n_in; (void)out_size; (void)ws_size;
  const float* x     = (const float*)d_in[0];
  const float* w_qkv = (const float*)d_in[1];
  const float* w_out = (const float*)d_in[2];
  const float* b_out = (const float*)d_in[3];
  float* out = (float*)d_out;

  float* ws = (float*)d_ws;
  float* Qs = ws;                               // 4 MB fp32 [bh][n][32]
  u16* K16  = (u16*)(ws + 1048576);             // 2 MB
  u16* VT16 = K16 + 1048576;                    // 2 MB
  float* AO = out;                              // in-place

  qkv_kernel<<<TOTROWS / QROWS, 384, 0, stream>>>(x, w_qkv, Qs, K16, VT16);
  attn_kernel<<<1024, 512, 0, stream>>>(Qs, K16, VT16, AO);
  outproj_kernel<<<TOTROWS / OROWS, 128, 0, stream>>>(AO, w_out, b_out, out);
}

// Round 20
// 67.702 us; speedup vs baseline: 1.2520x; 1.0745x over previous
//
#include <hip/hip_runtime.h>
#include <math.h>

#define HEADS   4
#define DH      32
#define NB      4096      // tokens per batch (D*H*W)
#define BATCH   2
#define C_IN    128
#define QKV_COLS 384
#define TOTROWS 8192      // BATCH * NB
#define ATT_EPS 1e-12f
#define C1      14.42695040888963f   // SCALE * log2(e), prefolded into Q
#define QROWS   8         // rows per qkv block (grid 1024)
#define OROWS   8         // rows per outproj block (grid 1024)

typedef __attribute__((ext_vector_type(16))) float f32x16;
typedef _Float16 f16x8 __attribute__((ext_vector_type(8)));
typedef __fp16 fp16x2 __attribute__((ext_vector_type(2)));   // cvt_pkrtz return type
typedef unsigned short u16;

// fp16 RTN conversion (default float->_Float16 rounding)
__device__ __forceinline__ u16 f16b(float a) {
  union { _Float16 h; u16 u; } t; t.h = (_Float16)a; return t.u;
}
__device__ __forceinline__ unsigned pkf16rtn(float a, float b) {
  return (unsigned)f16b(a) | ((unsigned)f16b(b) << 16);
}
// pack 2 f32 -> 2 f16 (RTZ), single instruction (P values only)
union Uh2 { fp16x2 h; unsigned u; };
__device__ __forceinline__ unsigned pkf16(float a, float b) {
  Uh2 t; t.h = __builtin_amdgcn_cvt_pkrtz(a, b); return t.u;
}
union U8h { unsigned u[4]; f16x8 h8; };
__device__ __forceinline__ f16x8 mk8h(unsigned a, unsigned b, unsigned c, unsigned d) {
  U8h t; t.u[0] = a; t.u[1] = b; t.u[2] = c; t.u[3] = d; return t.h8;
}
// v_permlane32_swap_b32 a,b. SAFE ONLY when a and b hold distinct values
// (else regalloc may coalesce them into one register) — see R4 post-mortem.
__device__ __forceinline__ void pl32swap(unsigned& a, unsigned& b) {
  asm("v_permlane32_swap_b32 %0, %1" : "+v"(a), "+v"(b));
}
#define GL16(gp, lp)                                                        \
  __builtin_amdgcn_global_load_lds(                                         \
      (const __attribute__((address_space(1))) void*)(gp),                  \
      (__attribute__((address_space(3))) void*)(lp), 16, 0, 0)

// ---------------------------------------------------------------------------
// QKV GEMM (x @ w_qkv) + fused L2-normalize of q,k. NO LDS (R12: scalar x
// loads; LDS-broadcast version was LDS-pipe-bound). Unchanged from R12.
// ---------------------------------------------------------------------------
__global__ __launch_bounds__(384) void qkv_kernel(
    const float* __restrict__ x, const float* __restrict__ w,
    float* __restrict__ Qs, u16* __restrict__ K16, u16* __restrict__ VT16) {
  const int tid = threadIdx.x;
  const int r0  = blockIdx.x * QROWS;

  float4 a4[QROWS];
#pragma unroll
  for (int r = 0; r < QROWS; ++r) a4[r] = make_float4(0.f, 0.f, 0.f, 0.f);

  for (int c4 = 0; c4 < 32; ++c4) {
    const float wv0 = w[(c4 * 4 + 0) * QKV_COLS + tid];
    const float wv1 = w[(c4 * 4 + 1) * QKV_COLS + tid];
    const float wv2 = w[(c4 * 4 + 2) * QKV_COLS + tid];
    const float wv3 = w[(c4 * 4 + 3) * QKV_COLS + tid];
#pragma unroll
    for (int r = 0; r < QROWS; ++r) {
      const float* xr = x + (size_t)(r0 + r) * C_IN + c4 * 4;  // uniform -> s_load
      a4[r].x = fmaf(xr[0], wv0, a4[r].x);
      a4[r].y = fmaf(xr[1], wv1, a4[r].y);
      a4[r].z = fmaf(xr[2], wv2, a4[r].z);
      a4[r].w = fmaf(xr[3], wv3, a4[r].w);
    }
  }

  float acc[QROWS];
#pragma unroll
  for (int r = 0; r < QROWS; ++r)
    acc[r] = (a4[r].x + a4[r].y) + (a4[r].z + a4[r].w);

  const int part = tid >> 7;   // 0=q 1=k 2=v (wave-uniform)
  if (part < 2) {
#pragma unroll
    for (int r = 0; r < QROWS; ++r) {
      float s = acc[r] * acc[r];
      s += __shfl_xor(s, 1, 32);
      s += __shfl_xor(s, 2, 32);
      s += __shfl_xor(s, 4, 32);
      s += __shfl_xor(s, 8, 32);
      s += __shfl_xor(s, 16, 32);
      acc[r] *= 1.0f / fmaxf(sqrtf(s), ATT_EPS);
    }
  }

  const int h = (tid >> 5) & 3, d = tid & 31;
  const int b = r0 >> 12, n0 = r0 & (NB - 1);
  const int bh = b * HEADS + h;
  if (part == 0) {
    float* dst = Qs + ((size_t)bh * NB + n0) * DH + d;
#pragma unroll
    for (int r = 0; r < QROWS; ++r) dst[(size_t)r * DH] = acc[r] * C1;
  } else if (part == 1) {
    const size_t kb = ((size_t)bh * NB + n0) * DH + d;
#pragma unroll
    for (int r = 0; r < QROWS; ++r) K16[kb + (size_t)r * DH] = f16b(acc[r]);
  } else {
    const size_t vb = ((size_t)bh * DH + d) * NB + n0;
#pragma unroll
    for (int r = 0; r < QROWS; r += 4) {
      uint2 hv;
      hv.x = pkf16rtn(acc[r + 0], acc[r + 1]);
      hv.y = pkf16rtn(acc[r + 2], acc[r + 3]);
      *(uint2*)(VT16 + vb + r) = hv;
    }
  }
}

// ---------------------------------------------------------------------------
// MFMA flash attention, fixed softmax max (|q.k|<=1 after L2 norm => log2
// scores bounded by C1; 2^-C1 cancels in O/L). No max tracking, no rescale.
// R20 = R12 geometry + T3/T4 counted-vmcnt pipeline (m218 pattern):
// TRIPLE-buffered LDS (3 x 16KB = 48KB), raw s_barrier (no drain), counted
// s_waitcnt vmcnt(2) — prefetched loads stay in flight ACROSS barriers.
// Ledger: prologue stages buf0,buf1 (2 GL16 each). Iter t: vmcnt(2) => own
// buf-t loads (oldest 2) landed; s_barrier => ALL waves' buf-t loads landed
// (each waited its own vmcnt first); compute buf t%3; stage buf (t+2)%3
// (safe: all waves passed this barrier => none still reads that buffer).
// R13's __syncthreads drained vmcnt to 0 every tile — that was the ~50%
// stall (R18/R19 showed TLP can't hide correlated waits).
// Block 512 = 8 waves = 2 qsub x 4 KV-splits; grid 512 (64 qp x 8 bh),
// XCD-pinned bh = id&7. QK^T and PV: fp16 single-term (R12).
// ---------------------------------------------------------------------------
__global__ __launch_bounds__(512, 4) void attn_kernel(
    const float* __restrict__ Qs, const u16* __restrict__ K16,
    const u16* __restrict__ VT16, float* __restrict__ AO) {
  // [buf(3)][split(4)][plane: 0=K 1=V][2048B] = 48 KB; merge overlays later
  __shared__ __align__(16) char sbuf[3][4][2][2048];

  const int tid  = threadIdx.x;
  const int lane = tid & 63;
  const int w    = tid >> 6;
  const int su   = w & 3;           // KV split
  const int u    = w >> 2;          // q-subtile
  const int q    = lane & 31;
  const int hi   = lane >> 5;
  const int bh   = blockIdx.x & 7;  // XCD-pinned panel
  const int qp   = blockIdx.x >> 3; // q-pair tile 0..63

  // ---- Q fragments (fp16 RTN); Q pre-scaled by C1 ----
  const int nrow = qp * 64 + u * 32 + q;
  const float* qrow = Qs + ((size_t)bh * NB + nrow) * DH;
  f16x8 fq16[2];
#pragma unroll
  for (int sl = 0; sl < 2; ++sl) {
    const int d0 = sl * 16 + hi * 8;
    const float4 a = *(const float4*)(qrow + d0);
    const float4 b = *(const float4*)(qrow + d0 + 4);
    fq16[sl] = mk8h(pkf16rtn(a.x, a.y), pkf16rtn(a.z, a.w),
                    pkf16rtn(b.x, b.y), pkf16rtn(b.z, b.w));
  }

  // ---- staging map: flat i = tid + it*512 over 8 planes x 2048B ----
  const u16* gp[2]; int gst[2], ldso[2];
#pragma unroll
  for (int it = 0; it < 2; ++it) {
    const int i    = tid + it * 512;
    const int pidx = i >> 7;            // plane 0..7 = split*2 + {K16,V16}
    const int sp   = pidx >> 1;
    const int pl   = pidx & 1;
    const int s    = i & 127;
    const int rtt  = s >> 2;            // row within plane (key or d)
    const int ps   = s & 3;             // physical 16B slot
    const int slot = ((ps ^ ((rtt >> 1) & 3)) << 3);   // logical, u16 units
    if (pl == 0) {  // K plane: row = key, advance 32 keys/tile
      gp[it]  = K16 + (size_t)bh * NB * DH + (size_t)(sp * 1024 + rtt) * DH + slot;
      gst[it] = 32 * DH;
    } else {        // V plane: row = d (NB-long), advance 32 u16/tile
      gp[it]  = VT16 + (size_t)bh * DH * NB + (size_t)rtt * NB + sp * 1024 + slot;
      gst[it] = 32;
    }
    ldso[it] = i * 16;
  }
  char* const sb = (char*)sbuf;
  auto stage = [&](int buf) {
#pragma unroll
    for (int it = 0; it < 2; ++it) {
      GL16(gp[it], sb + buf * 16384 + ldso[it]);
      gp[it] += gst[it];
    }
  };

  // read offsets (swizzled), constant per wave
  const int swq = (q >> 1) & 3;
  int koff[2];
#pragma unroll
  for (int i = 0; i < 2; ++i) koff[i] = q * 64 + (((i * 2 + hi) ^ swq) << 4);

  f32x16 oa, zz;
#pragma unroll
  for (int r = 0; r < 16; ++r) { oa[r] = 0.f; zz[r] = 0.f; }
  float lrun = 0.f;

  stage(0);   // tiles 0 and 1 in flight (2 GL16 each)
  stage(1);

  for (int t = 0; t < 32; ++t) {
    // own buf-(t%3) loads are the oldest 2 of (up to) 4 outstanding
    if (t < 31) asm volatile("s_waitcnt vmcnt(2)" ::: "memory");
    else        asm volatile("s_waitcnt vmcnt(0)" ::: "memory");
    __builtin_amdgcn_sched_barrier(0);
    __builtin_amdgcn_s_barrier();        // raw: no vmcnt drain
    __builtin_amdgcn_sched_barrier(0);

    const char* cb = sb + (t % 3) * 16384 + su * 4096;
    const char* ck = cb;
    const char* cv = cb + 2048;

    // ---- QK^T (single-term fp16), S^T[key][q]; C-in = const zero ----
    f32x16 sa;
    __builtin_amdgcn_s_setprio(1);
    {
      const f16x8 fk0 = *(const f16x8*)(ck + koff[0]);
      const f16x8 fk1 = *(const f16x8*)(ck + koff[1]);
      sa = __builtin_amdgcn_mfma_f32_32x32x16_f16(fk0, fq16[0], zz, 0, 0, 0);
      sa = __builtin_amdgcn_mfma_f32_32x32x16_f16(fk1, fq16[1], sa, 0, 0, 0);
    }
    __builtin_amdgcn_s_setprio(0);

    // ---- softmax, fixed max: raw v_exp_f32 (inputs bounded by ±~C1) ----
    float e[16], lsum = 0.f;
#pragma unroll
    for (int r = 0; r < 16; ++r) {
      e[r] = __builtin_amdgcn_exp2f(sa[r]);
      lsum += e[r];
    }
    lrun += lsum;

    // ---- P pack (fp16 RTZ) + permlane32_swap distribution, PV 1-term ----
    __builtin_amdgcn_s_setprio(1);
    {
      unsigned x0 = pkf16(e[0], e[1]), x1 = pkf16(e[2], e[3]);
      unsigned y0 = pkf16(e[4], e[5]), y1 = pkf16(e[6], e[7]);
      pl32swap(x0, y0);    // distinct values: safe
      pl32swap(x1, y1);
      const f16x8 fv0 = *(const f16x8*)(cv + koff[0]);
      oa = __builtin_amdgcn_mfma_f32_32x32x16_f16(fv0, mk8h(x0, x1, y0, y1),
                                                  oa, 0, 0, 0);
      unsigned z0 = pkf16(e[8], e[9]),   z1 = pkf16(e[10], e[11]);
      unsigned t0 = pkf16(e[12], e[13]), t1 = pkf16(e[14], e[15]);
      pl32swap(z0, t0);
      pl32swap(z1, t1);
      const f16x8 fv1 = *(const f16x8*)(cv + koff[1]);
      oa = __builtin_amdgcn_mfma_f32_32x32x16_f16(fv1, mk8h(z0, z1, t0, t1),
                                                  oa, 0, 0, 0);
    }
    __builtin_amdgcn_s_setprio(0);

    // stage tile t+2 into buf (t+2)%3 — all waves passed this iter's barrier,
    // so none still reads that buffer (it was consumed at iter t-1).
    if (t < 30) stage((t + 2) % 3);
    __builtin_amdgcn_sched_barrier(0);
  }

  // ---- 4-way split merge via LDS (plain sums — common fixed max) ----
  // Full barrier (drains everything) before overlaying dead staging LDS.
  __syncthreads();
  float* const mO = (float*)sbuf;             // [u][s(0..2)][q][33]
  float* const mL = mO + 2 * 3 * 32 * 33;     // [u][s][q]
  const float Lfull = lrun + __shfl_xor(lrun, 32);
  if (su != 0) {
    const int sidx = (u * 3 + (su - 1)) * 32 + q;
    if (hi == 0) mL[sidx] = Lfull;
#pragma unroll
    for (int r = 0; r < 16; ++r) {
      const int d = (r & 3) + 8 * (r >> 2) + 4 * hi;
      mO[sidx * 33 + d] = oa[r];
    }
  }
  __syncthreads();
  if (su == 0) {
    float Lt = Lfull;
#pragma unroll
    for (int s = 0; s < 3; ++s) Lt += mL[(u * 3 + s) * 32 + q];
    const float inv = 1.0f / Lt;
    const int b = bh >> 2, h = bh & 3;
    float* dst = AO + ((size_t)(b * NB + nrow)) * 128 + h * DH;
#pragma unroll
    for (int r = 0; r < 16; ++r) {
      const int d = (r & 3) + 8 * (r >> 2) + 4 * hi;
      float v = oa[r];
#pragma unroll
      for (int s = 0; s < 3; ++s) v += mO[((u * 3 + s) * 32 + q) * 33 + d];
      dst[d] = v * inv;
    }
  }
}

// ---------------------------------------------------------------------------
// out-proj GEMM: AO[8192][128] @ w_out[128][128] + b_out. NO LDS (R12).
// In-place safe: all AO reads complete before the barrier; stores after.
// ---------------------------------------------------------------------------
__global__ __launch_bounds__(128) void outproj_kernel(
    const float* __restrict__ AO, const float* __restrict__ w,
    const float* __restrict__ bias, float* __restrict__ out) {
  const int tid = threadIdx.x;
  const int r0  = blockIdx.x * OROWS;

  float4 a4[OROWS];
#pragma unroll
  for (int r = 0; r < OROWS; ++r) a4[r] = make_float4(0.f, 0.f, 0.f, 0.f);

  for (int c4 = 0; c4 < 32; ++c4) {
    const float wv0 = w[(c4 * 4 + 0) * 128 + tid];
    const float wv1 = w[(c4 * 4 + 1) * 128 + tid];
    const float wv2 = w[(c4 * 4 + 2) * 128 + tid];
    const float wv3 = w[(c4 * 4 + 3) * 128 + tid];
#pragma unroll
    for (int r = 0; r < OROWS; ++r) {
      const float* xr = AO + (size_t)(r0 + r) * 128 + c4 * 4;  // uniform -> s_load
      a4[r].x = fmaf(xr[0], wv0, a4[r].x);
      a4[r].y = fmaf(xr[1], wv1, a4[r].y);
      a4[r].z = fmaf(xr[2], wv2, a4[r].z);
      a4[r].w = fmaf(xr[3], wv3, a4[r].w);
    }
  }

  __syncthreads();   // all AO reads of this block's rows complete before stores

  const float bv = bias[tid];
#pragma unroll
  for (int r = 0; r < OROWS; ++r) {
    const float acc = (a4[r].x + a4[r].y) + (a4[r].z + a4[r].w);
    out[(size_t)(r0 + r) * 128 + tid] = acc + bv;
  }
}

// ---------------------------------------------------------------------------
extern "C" void kernel_launch(void* const* d_in, const int* in_sizes, int n_in,
                              void* d_out, int out_size, void* d_ws, size_t ws_size,
                              hipStream_t stream) {
  (void)in_sizes; (void)n_in; (void)out_size; (void)ws_size;
  const float* x     = (const float*)d_in[0];
  const float* w_qkv = (const float*)d_in[1];
  const float* w_out = (const float*)d_in[2];
  const float* b_out = (const float*)d_in[3];
  float* out = (float*)d_out;

  float* ws = (float*)d_ws;
  float* Qs = ws;                               // 4 MB fp32 [bh][n][32]
  u16* K16  = (u16*)(ws + 1048576);             // 2 MB
  u16* VT16 = K16 + 1048576;                    // 2 MB
  float* AO = out;                              // in-place

  qkv_kernel<<<TOTROWS / QROWS, 384, 0, stream>>>(x, w_qkv, Qs, K16, VT16);
  attn_kernel<<<512, 512, 0, stream>>>(Qs, K16, VT16, AO);
  outproj_kernel<<<TOTROWS / OROWS, 128, 0, stream>>>(AO, w_out, b_out, out);
}